// Round 12
// baseline (240.759 us; speedup 1.0000x reference)
//
#include <hip/hip_runtime.h>

#define DEVI __device__ __forceinline__
typedef unsigned short u16;
typedef unsigned int u32;
typedef __attribute__((ext_vector_type(4))) float f4v;
typedef __attribute__((ext_vector_type(8))) short bf8v;   // 8 bf16 for MFMA A/B
typedef __attribute__((ext_vector_type(4))) u32  u32x4;
typedef __attribute__((ext_vector_type(2))) u32  u32x2;
typedef __attribute__((ext_vector_type(4))) u16  u16x4;

#define AS1 __attribute__((address_space(1)))
#define AS3 __attribute__((address_space(3)))

DEVI u16 f2bf(float x){ union{float f;u32 u;} c{x}; u32 r=(c.u+0x7FFFu+((c.u>>16)&1u))>>16; return (u16)r; }
DEVI float bf2f(u16 b){ union{u32 u;float f;} c{(u32)b<<16}; return c.f; }
DEVI f4v mfma32(bf8v a, bf8v b, f4v c){ return __builtin_amdgcn_mfma_f32_16x16x32_bf16(a,b,c,0,0,0); }
DEVI unsigned lds_off(const void* p){ return (unsigned)(unsigned long)(AS3 const void*)p; }
DEVI void glds16(const void* g, void* l){
  __builtin_amdgcn_global_load_lds((AS1 void*)g, (AS3 void*)l, 16, 0, 0);
}

static constexpr int NH = 12, HW = 4096, D = 64, C = 768;
static constexpr float LOG2E = 1.44269504f;

// -------------- kernel 1: fused prep: convx + transp(wqkv) + transp(wo) --------------
__global__ void qa_prep(const float* __restrict__ x, u16* __restrict__ xb,
                        const float* __restrict__ wqkv, u16* __restrict__ wqkvt,
                        const float* __restrict__ wo,   u16* __restrict__ wot){
  __shared__ float tl[32][33];
  const int b = blockIdx.x, t = threadIdx.x;
  if(b < 3072){                       // convx: 3072*256 f4v = 12*4096*64 floats
    int i = b*256 + t;
    f4v v = ((const f4v*)x)[i];
    u16x4 o; for(int j=0;j<4;j++) o[j] = f2bf(v[j]);
    ((u16x4*)xb)[i] = o;
    return;
  }
  const float* in; u16* out; int R, Cc, scale_k, bx, by;
  if(b < 3072 + 1728){ int bb = b - 3072; in = wqkv; out = wqkvt; R = 768; Cc = 2304; scale_k = 1; bx = bb % 72; by = bb / 72; }
  else               { int bb = b - 4800; in = wo;   out = wot;   R = 768; Cc = 768;  scale_k = 0; bx = bb % 24; by = bb / 24; }
  int r0 = by*32, c0 = bx*32;
  int tr = t>>3, tc = (t&7)*4;
  f4v v = *(const f4v*)&in[(r0+tr)*Cc + c0 + tc];
  for(int j=0;j<4;j++) tl[tr][tc+j] = v[j];
  __syncthreads();
  int oc = t>>3, orr = (t&7)*4;
  float sc = (scale_k && (c0+oc) >= 768 && (c0+oc) < 1536) ? 0.125f*LOG2E : 1.0f;
  u16x4 o; for(int j=0;j<4;j++) o[j] = f2bf(tl[orr+j][oc]*sc);
  *(u16x4*)&out[(c0+oc)*R + r0 + orr] = o;
}

// ---- pipelined-GEMM (3-buf, race-free: vmcnt before barrier, issue after) ----
#define GEMM_STAGE(K0, BUF) \
  for(int i=0;i<2;i++){ \
    glds16(A  + (size_t)(m0+srow[i])*768 + (K0) + skk[i], (u16*)Al[BUF] + i*2048 + w*512); \
    glds16(Bt + (size_t)(n0+srow[i])*768 + (K0) + skk[i], (u16*)Bl[BUF] + i*2048 + w*512); }

#define GEMM_STEP(KIDX) { \
  if((KIDX) < 23) asm volatile("s_waitcnt vmcnt(4)\n\ts_barrier" ::: "memory"); \
  else            asm volatile("s_waitcnt vmcnt(0)\n\ts_barrier" ::: "memory"); \
  if((KIDX)+2 < 24) GEMM_STAGE(((KIDX)+2)*32, ((KIDX)+2)%3); \
  const int CUR=(KIDX)%3; \
  bf8v a[4], b[4]; \
  for(int mt=0;mt<4;mt++) a[mt] = *(const bf8v*)&Al[CUR][(wr*64+mt*16+c16)*32 + h4*8]; \
  for(int nt=0;nt<4;nt++) b[nt] = *(const bf8v*)&Bl[CUR][(wc*64+nt*16+c16)*32 + h4*8]; \
  __builtin_amdgcn_s_setprio(1); \
  for(int mt=0;mt<4;mt++) for(int nt=0;nt<4;nt++) acc[mt][nt] = mfma32(b[nt], a[mt], acc[mt][nt]); \
  __builtin_amdgcn_s_setprio(0); }

// -------------- kernel 3: QKV GEMM (4096 x 2304 x 768) --------------
__global__ __launch_bounds__(256,2) void qa_gemm_qkv(
    const u16* __restrict__ A, const u16* __restrict__ Bt, const float* __restrict__ bias,
    u16* __restrict__ qb, u16* __restrict__ kb, u16* __restrict__ vb){
  __shared__ u16 Al[3][4096], Bl[3][4096];
  const int t = threadIdx.x, lane = t&63, w = t>>6, c16 = lane&15, h4 = lane>>4;
  const int m0 = blockIdx.y*128, n0 = blockIdx.x*128;
  const int wr = w>>1, wc = w&1;
  f4v acc[4][4];
  for(int nt=0;nt<4;nt++){
    f4v bv;
    for(int r=0;r<4;r++){
      int col = n0 + wc*64 + nt*16 + 4*h4 + r;
      float b = bias[col];
      bv[r] = (col >= 768 && col < 1536) ? b*0.125f*LOG2E : b;
    }
    for(int mt=0;mt<4;mt++) acc[mt][nt] = bv;
  }
  int srow[2], skk[2];
  for(int i=0;i<2;i++){
    int off = i*4096 + w*1024 + lane*16;
    srow[i] = off>>6; skk[i] = (off&63)>>1;
  }
  GEMM_STAGE(0, 0); GEMM_STAGE(32, 1);
  #pragma unroll
  for(int p=0;p<8;p++){ GEMM_STEP(3*p); GEMM_STEP(3*p+1); GEMM_STEP(3*p+2); }
  for(int mt=0;mt<4;mt++){
    int row = m0 + wr*64 + mt*16 + c16;
    for(int nt=0;nt<4;nt++){
      int col0 = n0 + wc*64 + nt*16 + 4*h4;
      int which = col0/768, head = (col0>>6)%12, d0 = col0&63;
      u16* dst = which==0 ? qb : (which==1 ? kb : vb);
      u32x2 pk;
      asm("v_cvt_pk_bf16_f32 %0, %1, %2" : "=v"(pk[0]) : "v"(acc[mt][nt][0]), "v"(acc[mt][nt][1]));
      asm("v_cvt_pk_bf16_f32 %0, %1, %2" : "=v"(pk[1]) : "v"(acc[mt][nt][2]), "v"(acc[mt][nt][3]));
      *(u32x2*)&dst[((size_t)(head<<12)+row)*64 + d0] = pk;
    }
  }
}

// -------------- kernel 4: rel-pos bias tables via MFMA (scaled by log2e) --------------
__global__ __launch_bounds__(256) void qa_rel(
    const u16* __restrict__ qbuf, const float* __restrict__ rph, const float* __restrict__ rpw,
    u16* __restrict__ RHt, u16* __restrict__ RW){
  const int t = threadIdx.x, lane = t&63, w = t>>6, c16 = lane&15, h4 = lane>>4;
  const int qh = blockIdx.x, head = blockIdx.y;
  __shared__ u16 ql[64*72], hl[64*72], wl[128*72];
  {
    int row = t>>2, d0 = (t&3)*16;
    const u16* src = qbuf + ((size_t)(head<<12)+(qh<<6)+row)*64 + d0;
    *(u32x4*)&ql[row*72+d0]   = *(const u32x4*)src;
    *(u32x4*)&ql[row*72+d0+8] = *(const u32x4*)(src+8);
    for(int j=0;j<16;j+=4){
      f4v v = *(const f4v*)&rph[(qh+row)*64 + d0 + j];
      u32x2 pk;
      asm("v_cvt_pk_bf16_f32 %0, %1, %2" : "=v"(pk[0]) : "v"(v[0]), "v"(v[1]));
      asm("v_cvt_pk_bf16_f32 %0, %1, %2" : "=v"(pk[1]) : "v"(v[2]), "v"(v[3]));
      *(u32x2*)&hl[row*72+d0+j] = pk;
    }
    int rw_r = t>>1, rd0 = (t&1)*32;
    if(rw_r < 127){
      for(int j=0;j<32;j+=4){
        f4v v = *(const f4v*)&rpw[rw_r*64+rd0+j];
        u32x2 pk;
        asm("v_cvt_pk_bf16_f32 %0, %1, %2" : "=v"(pk[0]) : "v"(v[0]), "v"(v[1]));
        asm("v_cvt_pk_bf16_f32 %0, %1, %2" : "=v"(pk[1]) : "v"(v[2]), "v"(v[3]));
        *(u32x2*)&wl[rw_r*72+rd0+j] = pk;
      }
    } else {
      for(int j=0;j<32;j+=4) *(u32x2*)&wl[rw_r*72+rd0+j] = (u32x2){0u,0u};
    }
  }
  __syncthreads();
  if(w < 2){
    bf8v a[2][2]; f4v acc[2][4] = {};
    for(int mt=0;mt<2;mt++) for(int ch=0;ch<2;ch++)
      a[mt][ch] = *(const bf8v*)&ql[(w*32+mt*16+c16)*72 + ch*32 + h4*8];
    for(int nt=0;nt<4;nt++) for(int ch=0;ch<2;ch++){
      bf8v b = *(const bf8v*)&hl[(nt*16+c16)*72 + ch*32 + h4*8];
      for(int mt=0;mt<2;mt++) acc[mt][nt] = mfma32(a[mt][ch], b, acc[mt][nt]);
    }
    for(int mt=0;mt<2;mt++) for(int nt=0;nt<4;nt++) for(int r=0;r<4;r++){
      int qw = w*32+mt*16+4*h4+r, c = nt*16+c16, kh = 63 - c;
      RHt[((size_t)(head*64+qh)*64+kh)*64 + qw] = f2bf(acc[mt][nt][r]*LOG2E);
    }
  } else {
    bf8v a[2][2]; f4v acc[2][8] = {};
    for(int mt=0;mt<2;mt++) for(int ch=0;ch<2;ch++)
      a[mt][ch] = *(const bf8v*)&ql[((w-2)*32+mt*16+c16)*72 + ch*32 + h4*8];
    for(int nt=0;nt<8;nt++) for(int ch=0;ch<2;ch++){
      bf8v b = *(const bf8v*)&wl[(nt*16+c16)*72 + ch*32 + h4*8];
      for(int mt=0;mt<2;mt++) acc[mt][nt] = mfma32(a[mt][ch], b, acc[mt][nt]);
    }
    for(int mt=0;mt<2;mt++) for(int nt=0;nt<8;nt++) for(int r=0;r<4;r++){
      int qw = (w-2)*32+mt*16+4*h4+r, c = nt*16+c16, kw = qw + 63 - c;
      if((unsigned)kw < 64u) RW[((size_t)(head*64+qh)*64+qw)*64 + kw] = f2bf(acc[mt][nt][r]*LOG2E);
    }
  }
}

// -------------- kernel 5: fused flash attention, split-K x4 (qc=2 proven geometry) --------------
// grid 1536 (XCD-swizzled): block = (head, qblk of 128 rows, s in [0,4)); 4 waves x 32 qrows; 16 k-tiles.
// Iter body/protocol byte-identical to R6/R9/R11; only constants changed (16 iters, s*65536, RHl[2][1024]).
#define AITER(IT, CUR) { \
    asm volatile("s_barrier" ::: "memory"); \
    if((IT) == 15){ kp = kg; vp = vg; } \
    { u16* Kn = (u16*)Kl[(CUR)^1]; u16* Vn = (u16*)Vl[(CUR)^1]; \
      for(int i=0;i<2;i++){ \
        glds16(kp + koff[i], Kn + (i*256 + w*64)*8); \
        glds16(vp + voff[i], Vn + (i*256 + w*64)*8); } } \
    kp += 4096; vp += 4096; \
    asm volatile("s_waitcnt vmcnt(4)" ::: "memory"); \
    const char* Kc = (const char*)Kl[CUR]; \
    float rh0 = bf2f(RHl[qhl][(IT)*64 + (w&1)*32 + c16]); \
    float rh1 = bf2f(RHl[qhl][(IT)*64 + (w&1)*32 + 16 + c16]); \
    f4v p[4][2]; \
    _Pragma("unroll") \
    for(int nt=0;nt<4;nt++){ \
      bf8v k0 = *(const bf8v*)(Kc + kA + nt*2048 + kq0); \
      bf8v k1 = *(const bf8v*)(Kc + kA + nt*2048 + kq1); \
      _Pragma("unroll") \
      for(int qc=0;qc<2;qc++){ \
        f4v sv; float rh = qc ? rh1 : rh0; \
        for(int r=0;r<4;r++) sv[r] = rh + rw[nt][qc][r]; \
        __builtin_amdgcn_s_setprio(1); \
        sv = mfma32(k0, qa[qc][0], sv); \
        sv = mfma32(k1, qa[qc][1], sv); \
        __builtin_amdgcn_s_setprio(0); \
        f4v pe; \
        for(int r=0;r<4;r++) pe[r] = __builtin_amdgcn_exp2f(sv[r]); \
        p[nt][qc] = pe; } } \
    union U8 { u32 wd[4]; bf8v v; }; \
    U8 pb[2][2]; \
    _Pragma("unroll") \
    for(int half=0;half<2;half++) \
      for(int qc=0;qc<2;qc++) \
        for(int i=0;i<4;i++){ \
          int nt = half*2 + (i>>1), r0 = (i&1)*2; \
          asm("v_cvt_pk_bf16_f32 %0, %1, %2" \
              : "=v"(pb[half][qc].wd[i]) : "v"(p[nt][qc][r0]), "v"(p[nt][qc][r0+1])); } \
    _Pragma("unroll") \
    for(int qc=0;qc<2;qc++){ \
      psacc[qc] = mfma32(onesv, pb[0][qc].v, psacc[qc]); \
      psacc[qc] = mfma32(onesv, pb[1][qc].v, psacc[qc]); } \
    unsigned vcur = vbase + (CUR)*8192; \
    _Pragma("unroll") \
    for(int dt=0;dt<4;dt++){ \
      unsigned long t00,t01,t10,t11; \
      asm volatile( \
        "ds_read_b64_tr_b16 %0, %4 offset:%c5\n\t" \
        "ds_read_b64_tr_b16 %1, %4 offset:%c6\n\t" \
        "ds_read_b64_tr_b16 %2, %4 offset:%c7\n\t" \
        "ds_read_b64_tr_b16 %3, %4 offset:%c8\n\t" \
        "s_waitcnt lgkmcnt(0)" \
        : "=&v"(t00), "=&v"(t01), "=&v"(t10), "=&v"(t11) \
        : "v"(vcur), "i"((dt)*2048), "i"((dt)*2048+512), "i"((dt)*2048+1024), "i"((dt)*2048+1536) \
        : "memory"); \
      union PV { struct{ unsigned long a,b; } q; bf8v v; }; \
      PV v01, v23; \
      v01.q.a = t00; v01.q.b = t01; v23.q.a = t10; v23.q.b = t11; \
      __builtin_amdgcn_s_setprio(1); \
      _Pragma("unroll") \
      for(int qc=0;qc<2;qc++){ \
        oacc[dt][qc] = mfma32(v01.v, pb[0][qc].v, oacc[dt][qc]); \
        oacc[dt][qc] = mfma32(v23.v, pb[1][qc].v, oacc[dt][qc]); } \
      __builtin_amdgcn_s_setprio(0); } \
  }

__global__ __launch_bounds__(256,4) void qa_attn(
    const u16* __restrict__ qb, const u16* __restrict__ kb, const u16* __restrict__ vb,
    const u16* __restrict__ RHt, const u16* __restrict__ RW,
    u16* __restrict__ Op, float* __restrict__ Ps){
  __shared__ u16 Kl[2][4096];   // [buf][key][d], content at byte b = K[b ^ ((b>>7&7)<<4)]
  __shared__ u16 Vl[2][4096];   // [buf], subtiled: (d>>4)*2048B + key*32B + (d&15)*2B
  __shared__ u16 RHl[2][1024];  // [qhl][kh_local(16)][qw(64)]
  const int t = threadIdx.x, lane = t&63, w = t>>6, c16 = lane&15, h4 = lane>>4;
  const int bid = blockIdx.x;
  const int g = (bid&7)*192 + (bid>>3);       // XCD swizzle (bijective, 1536 % 8 == 0)
  const int s = g&3, u = g>>2;                // u in [0,384)
  const int head = u>>5, qblk = u&31;
  const int B0 = qblk*128;
  const int qhl = w>>1;                       // this wave's qh within block

  // prologue: stage RH [2][16][64] (waves 0,1 -> chunk 0; waves 2,3 -> chunk 1)
  {
    const u16* rhsrc = RHt + (((size_t)(head*64 + qblk*2 + qhl))*64 + s*16)*64;
    glds16(rhsrc + (w&1)*512 + lane*8, (u16*)RHl[qhl] + (w&1)*512);
  }
  // staging source offsets (16B units), fold K swizzle / V subtile permutation into source
  int koff[2], voff[2];
  for(int i=0;i<2;i++){
    int uu = i*256 + t;
    koff[i] = (uu ^ ((uu>>3)&7))*8;                    // elements
    int key = ((uu>>1)&3) | (((uu>>3)&15)<<2);
    int d0  = ((uu&1)<<3) | (((uu>>7)&3)<<4);
    voff[i] = key*64 + d0;
  }
  const u16* kg = kb + (size_t)head*262144 + (size_t)s*65536;
  const u16* vg = vb + (size_t)head*262144 + (size_t)s*65536;
  const u16* kp = kg; const u16* vp = vg;
  for(int i=0;i<2;i++){                                 // tile 0 -> buf 0
    glds16(kp + koff[i], (u16*)Kl[0] + (i*256 + w*64)*8);
    glds16(vp + voff[i], (u16*)Vl[0] + (i*256 + w*64)*8);
  }
  kp += 4096; vp += 4096;

  // Q fragments (B-operand): lane holds Q[qrow = B0 + w*32 + qc*16 + c16][d = 8*h4+j]
  bf8v qa[2][2];
  for(int qc=0;qc<2;qc++){
    const u16* qsrc = qb + ((size_t)head*4096 + B0 + w*32 + qc*16 + c16)*64;
    qa[qc][0] = *(const bf8v*)(qsrc + h4*8);
    qa[qc][1] = *(const bf8v*)(qsrc + 32 + h4*8);
  }
  // RW bias in registers: rw[nt][qc][r] for kw = nt*16+4*h4+r (already *log2e)
  float rw[4][2][4];
  for(int nt=0;nt<4;nt++) for(int qc=0;qc<2;qc++) for(int r=0;r<4;r++){
    int qw = (w&1)*32 + qc*16 + c16, kw = nt*16 + 4*h4 + r;
    rw[nt][qc][r] = bf2f(RW[(((size_t)(head*64 + qblk*2 + qhl))*64 + qw)*64 + kw]);
  }
  bf8v onesv; for(int j=0;j<8;j++) onesv[j] = (short)0x3F80;  // bf16 1.0

  f4v oacc[4][2] = {}; f4v psacc[2] = {};
  const unsigned vbase = lds_off(Vl) + lane*8;
  const int kq0 = (h4*16) ^ ((c16&7)<<4);
  const int kq1 = (h4*16 + 64) ^ ((c16&7)<<4);
  const int kA  = c16*128;

  for(int itp=0; itp<8; itp++){
    AITER(2*itp, 0);
    AITER(2*itp+1, 1);
  }
  asm volatile("s_waitcnt vmcnt(0)" ::: "memory");  // drain wrap-around DMA before exit

  #pragma unroll
  for(int qc=0;qc<2;qc++){
    float v = psacc[qc][0];     // ones-MFMA row-sum: identical across h4/r, col = qrow = c16
    const int qrow_l = w*32 + qc*16 + c16;
    if(h4 == 0) Ps[((size_t)u*4 + s)*128 + qrow_l] = v;
    const size_t obase = (((size_t)u*4 + s)*128 + qrow_l)*64;
    #pragma unroll
    for(int dt=0;dt<4;dt++){
      u32x2 pk;
      asm("v_cvt_pk_bf16_f32 %0, %1, %2" : "=v"(pk[0]) : "v"(oacc[dt][qc][0]), "v"(oacc[dt][qc][1]));
      asm("v_cvt_pk_bf16_f32 %0, %1, %2" : "=v"(pk[1]) : "v"(oacc[dt][qc][2]), "v"(oacc[dt][qc][3]));
      *(u32x2*)&Op[obase + dt*16 + 4*h4] = pk;
    }
  }
}

// -------------- kernel 5b: 4-way split-K reduce: o = (O0+..+O3)/(s0+..+s3) --------------
__global__ __launch_bounds__(256) void qa_reduce(
    const u16* __restrict__ Op, const float* __restrict__ Ps, u16* __restrict__ ob){
  const int u = blockIdx.x, t = threadIdx.x;     // u in [0,384)
  const int head = u>>5, qblk = u&31;
  const int d0 = (t&15)*4;
  const size_t base = (size_t)u*4*128;
  #pragma unroll
  for(int qq=0;qq<8;qq++){
    int qr = (t>>4) + qq*16;
    float tot = 0.f;
    #pragma unroll
    for(int s2=0;s2<4;s2++) tot += Ps[base + s2*128 + qr];
    float inv = 1.0f/tot;
    float a[4] = {0,0,0,0};
    #pragma unroll
    for(int s2=0;s2<4;s2++){
      u16x4 v = *(const u16x4*)&Op[(base + s2*128 + qr)*64 + d0];
      for(int j=0;j<4;j++) a[j] += bf2f(v[j]);
    }
    u16x4 o;
    for(int j=0;j<4;j++) o[j] = f2bf(a[j]*inv);
    *(u16x4*)&ob[(size_t)(qblk*128 + qr)*768 + head*64 + d0] = o;
  }
}

// -------------- kernel 6: output GEMM (4096 x 768 x 768) --------------
__global__ __launch_bounds__(256,2) void qa_gemm_out(
    const u16* __restrict__ A, const u16* __restrict__ Bt, const float* __restrict__ bias,
    float* __restrict__ out){
  __shared__ u16 Al[3][4096], Bl[3][4096];
  const int t = threadIdx.x, lane = t&63, w = t>>6, c16 = lane&15, h4 = lane>>4;
  const int m0 = blockIdx.y*128, n0 = blockIdx.x*128;
  const int wr = w>>1, wc = w&1;
  f4v acc[4][4];
  for(int nt=0;nt<4;nt++){
    f4v bv = *(const f4v*)&bias[n0 + wc*64 + nt*16 + 4*h4];
    for(int mt=0;mt<4;mt++) acc[mt][nt] = bv;
  }
  int srow[2], skk[2];
  for(int i=0;i<2;i++){
    int off = i*4096 + w*1024 + lane*16;
    srow[i] = off>>6; skk[i] = (off&63)>>1;
  }
  GEMM_STAGE(0, 0); GEMM_STAGE(32, 1);
  #pragma unroll
  for(int p=0;p<8;p++){ GEMM_STEP(3*p); GEMM_STEP(3*p+1); GEMM_STEP(3*p+2); }
  for(int mt=0;mt<4;mt++){
    int row = m0 + wr*64 + mt*16 + c16;
    for(int nt=0;nt<4;nt++){
      int col0 = n0 + wc*64 + nt*16 + 4*h4;
      *(f4v*)&out[(size_t)row*768 + col0] = acc[mt][nt];
    }
  }
}

extern "C" void kernel_launch(void* const* d_in, const int* in_sizes, int n_in,
                              void* d_out, int out_size, void* d_ws, size_t ws_size,
                              hipStream_t stream){
  const float* x    = (const float*)d_in[0];
  const float* wqkv = (const float*)d_in[1];
  const float* bqkv = (const float*)d_in[2];
  const float* wo   = (const float*)d_in[3];
  const float* bo   = (const float*)d_in[4];
  const float* rph  = (const float*)d_in[5];
  const float* rpw  = (const float*)d_in[6];
  float* out = (float*)d_out;

  // Compact aliased workspace (58.6 MB):
  //   op_buf [0, 25.17M) overlays x_bf + wqkv_t (both dead after gemm_qkv; attn writes op after)
  //   o_buf overlays rh_buf (dead after attn; reduce writes o after attn completes)
  char* W = (char*)d_ws;
  u16*   op_buf = (u16*)(W + 0);                 // 25,165,824 B (384*4*128*64*2)
  u16*   x_bf   = (u16*)(W + 0);                 //  6,291,456 B
  u16*   wqkv_t = (u16*)(W + 6291456);           //  3,538,944 B
  float* ps_buf = (float*)(W + 25165824);        //    786,432 B (384*4*128*4)
  u16*   wo_t   = (u16*)(W + 25952256);          //  1,179,648 B
  u16*   q_buf  = (u16*)(W + 27131904);          //  6,291,456 B
  u16*   k_buf  = (u16*)(W + 33423360);          //  6,291,456 B
  u16*   v_buf  = (u16*)(W + 39714816);          //  6,291,456 B
  u16*   rh_buf = (u16*)(W + 46006272);          //  6,291,456 B
  u16*   o_buf  = (u16*)(W + 46006272);          //  aliases rh_buf
  u16*   rw_buf = (u16*)(W + 52297728);          //  6,291,456 B -> total 58,589,184

  qa_prep<<<5376, 256, 0, stream>>>(x, x_bf, wqkv, wqkv_t, wo, wo_t);
  qa_gemm_qkv<<<dim3(2304/128, HW/128), 256, 0, stream>>>(x_bf, wqkv_t, bqkv, q_buf, k_buf, v_buf);
  qa_rel<<<dim3(64, NH), 256, 0, stream>>>(q_buf, rph, rpw, rh_buf, rw_buf);
  qa_attn<<<1536, 256, 0, stream>>>(q_buf, k_buf, v_buf, rh_buf, rw_buf, op_buf, ps_buf);
  qa_reduce<<<384, 256, 0, stream>>>(op_buf, ps_buf, o_buf);
  qa_gemm_out<<<dim3(768/128, HW/128), 256, 0, stream>>>(o_buf, wo_t, bo, out);
}

// Round 13
// 132.942 us; speedup vs baseline: 1.8110x; 1.8110x over previous
//
#include <hip/hip_runtime.h>

#define DEVI __device__ __forceinline__
typedef unsigned short u16;
typedef unsigned int u32;
typedef __attribute__((ext_vector_type(4))) float f4v;
typedef __attribute__((ext_vector_type(8))) short bf8v;   // 8 bf16 for MFMA A/B
typedef __attribute__((ext_vector_type(4))) u32  u32x4;
typedef __attribute__((ext_vector_type(2))) u32  u32x2;
typedef __attribute__((ext_vector_type(4))) u16  u16x4;

#define AS1 __attribute__((address_space(1)))
#define AS3 __attribute__((address_space(3)))

DEVI u16 f2bf(float x){ union{float f;u32 u;} c{x}; u32 r=(c.u+0x7FFFu+((c.u>>16)&1u))>>16; return (u16)r; }
DEVI float bf2f(u16 b){ union{u32 u;float f;} c{(u32)b<<16}; return c.f; }
DEVI f4v mfma32(bf8v a, bf8v b, f4v c){ return __builtin_amdgcn_mfma_f32_16x16x32_bf16(a,b,c,0,0,0); }
DEVI unsigned lds_off(const void* p){ return (unsigned)(unsigned long)(AS3 const void*)p; }
DEVI void glds16(const void* g, void* l){
  __builtin_amdgcn_global_load_lds((AS1 void*)g, (AS3 void*)l, 16, 0, 0);
}

static constexpr int NH = 12, HW = 4096, D = 64, C = 768;
static constexpr float LOG2E = 1.44269504f;

// -------------- kernel 1: fused prep: convx + transp(wqkv) + transp(wo) --------------
__global__ void qa_prep(const float* __restrict__ x, u16* __restrict__ xb,
                        const float* __restrict__ wqkv, u16* __restrict__ wqkvt,
                        const float* __restrict__ wo,   u16* __restrict__ wot){
  __shared__ float tl[32][33];
  const int b = blockIdx.x, t = threadIdx.x;
  if(b < 3072){                       // convx: 3072*256 f4v = 12*4096*64 floats
    int i = b*256 + t;
    f4v v = ((const f4v*)x)[i];
    u16x4 o; for(int j=0;j<4;j++) o[j] = f2bf(v[j]);
    ((u16x4*)xb)[i] = o;
    return;
  }
  const float* in; u16* out; int R, Cc, scale_k, bx, by;
  if(b < 3072 + 1728){ int bb = b - 3072; in = wqkv; out = wqkvt; R = 768; Cc = 2304; scale_k = 1; bx = bb % 72; by = bb / 72; }
  else               { int bb = b - 4800; in = wo;   out = wot;   R = 768; Cc = 768;  scale_k = 0; bx = bb % 24; by = bb / 24; }
  int r0 = by*32, c0 = bx*32;
  int tr = t>>3, tc = (t&7)*4;
  f4v v = *(const f4v*)&in[(r0+tr)*Cc + c0 + tc];
  for(int j=0;j<4;j++) tl[tr][tc+j] = v[j];
  __syncthreads();
  int oc = t>>3, orr = (t&7)*4;
  float sc = (scale_k && (c0+oc) >= 768 && (c0+oc) < 1536) ? 0.125f*LOG2E : 1.0f;
  u16x4 o; for(int j=0;j<4;j++) o[j] = f2bf(tl[orr+j][oc]*sc);
  *(u16x4*)&out[(c0+oc)*R + r0 + orr] = o;
}

// ---- pipelined-GEMM (3-buf, race-free: vmcnt before barrier, issue after) ----
#define GEMM_STAGE(K0, BUF) \
  for(int i=0;i<2;i++){ \
    glds16(A  + (size_t)(m0+srow[i])*768 + (K0) + skk[i], (u16*)Al[BUF] + i*2048 + w*512); \
    glds16(Bt + (size_t)(n0+srow[i])*768 + (K0) + skk[i], (u16*)Bl[BUF] + i*2048 + w*512); }

#define GEMM_STEP(KIDX) { \
  if((KIDX) < 23) asm volatile("s_waitcnt vmcnt(4)\n\ts_barrier" ::: "memory"); \
  else            asm volatile("s_waitcnt vmcnt(0)\n\ts_barrier" ::: "memory"); \
  if((KIDX)+2 < 24) GEMM_STAGE(((KIDX)+2)*32, ((KIDX)+2)%3); \
  const int CUR=(KIDX)%3; \
  bf8v a[4], b[4]; \
  for(int mt=0;mt<4;mt++) a[mt] = *(const bf8v*)&Al[CUR][(wr*64+mt*16+c16)*32 + h4*8]; \
  for(int nt=0;nt<4;nt++) b[nt] = *(const bf8v*)&Bl[CUR][(wc*64+nt*16+c16)*32 + h4*8]; \
  __builtin_amdgcn_s_setprio(1); \
  for(int mt=0;mt<4;mt++) for(int nt=0;nt<4;nt++) acc[mt][nt] = mfma32(b[nt], a[mt], acc[mt][nt]); \
  __builtin_amdgcn_s_setprio(0); }

// -------------- kernel 3: QKV GEMM (4096 x 2304 x 768) --------------
__global__ __launch_bounds__(256,2) void qa_gemm_qkv(
    const u16* __restrict__ A, const u16* __restrict__ Bt, const float* __restrict__ bias,
    u16* __restrict__ qb, u16* __restrict__ kb, u16* __restrict__ vb){
  __shared__ u16 Al[3][4096], Bl[3][4096];
  const int t = threadIdx.x, lane = t&63, w = t>>6, c16 = lane&15, h4 = lane>>4;
  const int m0 = blockIdx.y*128, n0 = blockIdx.x*128;
  const int wr = w>>1, wc = w&1;
  f4v acc[4][4];
  for(int nt=0;nt<4;nt++){
    f4v bv;
    for(int r=0;r<4;r++){
      int col = n0 + wc*64 + nt*16 + 4*h4 + r;
      float b = bias[col];
      bv[r] = (col >= 768 && col < 1536) ? b*0.125f*LOG2E : b;
    }
    for(int mt=0;mt<4;mt++) acc[mt][nt] = bv;
  }
  int srow[2], skk[2];
  for(int i=0;i<2;i++){
    int off = i*4096 + w*1024 + lane*16;
    srow[i] = off>>6; skk[i] = (off&63)>>1;
  }
  GEMM_STAGE(0, 0); GEMM_STAGE(32, 1);
  #pragma unroll
  for(int p=0;p<8;p++){ GEMM_STEP(3*p); GEMM_STEP(3*p+1); GEMM_STEP(3*p+2); }
  for(int mt=0;mt<4;mt++){
    int row = m0 + wr*64 + mt*16 + c16;
    for(int nt=0;nt<4;nt++){
      int col0 = n0 + wc*64 + nt*16 + 4*h4;
      int which = col0/768, head = (col0>>6)%12, d0 = col0&63;
      u16* dst = which==0 ? qb : (which==1 ? kb : vb);
      u32x2 pk;
      asm("v_cvt_pk_bf16_f32 %0, %1, %2" : "=v"(pk[0]) : "v"(acc[mt][nt][0]), "v"(acc[mt][nt][1]));
      asm("v_cvt_pk_bf16_f32 %0, %1, %2" : "=v"(pk[1]) : "v"(acc[mt][nt][2]), "v"(acc[mt][nt][3]));
      *(u32x2*)&dst[((size_t)(head<<12)+row)*64 + d0] = pk;
    }
  }
}

// -------------- kernel 4: rel-pos bias tables via MFMA (scaled by log2e) --------------
__global__ __launch_bounds__(256) void qa_rel(
    const u16* __restrict__ qbuf, const float* __restrict__ rph, const float* __restrict__ rpw,
    u16* __restrict__ RHt, u16* __restrict__ RW){
  const int t = threadIdx.x, lane = t&63, w = t>>6, c16 = lane&15, h4 = lane>>4;
  const int qh = blockIdx.x, head = blockIdx.y;
  __shared__ u16 ql[64*72], hl[64*72], wl[128*72];
  {
    int row = t>>2, d0 = (t&3)*16;
    const u16* src = qbuf + ((size_t)(head<<12)+(qh<<6)+row)*64 + d0;
    *(u32x4*)&ql[row*72+d0]   = *(const u32x4*)src;
    *(u32x4*)&ql[row*72+d0+8] = *(const u32x4*)(src+8);
    for(int j=0;j<16;j+=4){
      f4v v = *(const f4v*)&rph[(qh+row)*64 + d0 + j];
      u32x2 pk;
      asm("v_cvt_pk_bf16_f32 %0, %1, %2" : "=v"(pk[0]) : "v"(v[0]), "v"(v[1]));
      asm("v_cvt_pk_bf16_f32 %0, %1, %2" : "=v"(pk[1]) : "v"(v[2]), "v"(v[3]));
      *(u32x2*)&hl[row*72+d0+j] = pk;
    }
    int rw_r = t>>1, rd0 = (t&1)*32;
    if(rw_r < 127){
      for(int j=0;j<32;j+=4){
        f4v v = *(const f4v*)&rpw[rw_r*64+rd0+j];
        u32x2 pk;
        asm("v_cvt_pk_bf16_f32 %0, %1, %2" : "=v"(pk[0]) : "v"(v[0]), "v"(v[1]));
        asm("v_cvt_pk_bf16_f32 %0, %1, %2" : "=v"(pk[1]) : "v"(v[2]), "v"(v[3]));
        *(u32x2*)&wl[rw_r*72+rd0+j] = pk;
      }
    } else {
      for(int j=0;j<32;j+=4) *(u32x2*)&wl[rw_r*72+rd0+j] = (u32x2){0u,0u};
    }
  }
  __syncthreads();
  if(w < 2){
    bf8v a[2][2]; f4v acc[2][4] = {};
    for(int mt=0;mt<2;mt++) for(int ch=0;ch<2;ch++)
      a[mt][ch] = *(const bf8v*)&ql[(w*32+mt*16+c16)*72 + ch*32 + h4*8];
    for(int nt=0;nt<4;nt++) for(int ch=0;ch<2;ch++){
      bf8v b = *(const bf8v*)&hl[(nt*16+c16)*72 + ch*32 + h4*8];
      for(int mt=0;mt<2;mt++) acc[mt][nt] = mfma32(a[mt][ch], b, acc[mt][nt]);
    }
    for(int mt=0;mt<2;mt++) for(int nt=0;nt<4;nt++) for(int r=0;r<4;r++){
      int qw = w*32+mt*16+4*h4+r, c = nt*16+c16, kh = 63 - c;
      RHt[((size_t)(head*64+qh)*64+kh)*64 + qw] = f2bf(acc[mt][nt][r]*LOG2E);
    }
  } else {
    bf8v a[2][2]; f4v acc[2][8] = {};
    for(int mt=0;mt<2;mt++) for(int ch=0;ch<2;ch++)
      a[mt][ch] = *(const bf8v*)&ql[((w-2)*32+mt*16+c16)*72 + ch*32 + h4*8];
    for(int nt=0;nt<8;nt++) for(int ch=0;ch<2;ch++){
      bf8v b = *(const bf8v*)&wl[(nt*16+c16)*72 + ch*32 + h4*8];
      for(int mt=0;mt<2;mt++) acc[mt][nt] = mfma32(a[mt][ch], b, acc[mt][nt]);
    }
    for(int mt=0;mt<2;mt++) for(int nt=0;nt<8;nt++) for(int r=0;r<4;r++){
      int qw = (w-2)*32+mt*16+4*h4+r, c = nt*16+c16, kw = qw + 63 - c;
      if((unsigned)kw < 64u) RW[((size_t)(head*64+qh)*64+qw)*64 + kw] = f2bf(acc[mt][nt][r]*LOG2E);
    }
  }
}

// -------------- kernel 5: fused flash attention (R6/R9/R11-proven, byte-identical) --------------
// grid 768 (XCD-swizzled): block = (head, qblk of 128 rows, s); 4 waves x 32 qrows; 32 k-tiles.
#define AITER(IT, CUR) { \
    asm volatile("s_barrier" ::: "memory"); \
    if((IT) == 31){ kp = kg; vp = vg; } \
    { u16* Kn = (u16*)Kl[(CUR)^1]; u16* Vn = (u16*)Vl[(CUR)^1]; \
      for(int i=0;i<2;i++){ \
        glds16(kp + koff[i], Kn + (i*256 + w*64)*8); \
        glds16(vp + voff[i], Vn + (i*256 + w*64)*8); } } \
    kp += 4096; vp += 4096; \
    asm volatile("s_waitcnt vmcnt(4)" ::: "memory"); \
    const char* Kc = (const char*)Kl[CUR]; \
    float rh0 = bf2f(RHl[qhl*2048 + (IT)*64 + (w&1)*32 + c16]); \
    float rh1 = bf2f(RHl[qhl*2048 + (IT)*64 + (w&1)*32 + 16 + c16]); \
    f4v p[4][2]; \
    _Pragma("unroll") \
    for(int nt=0;nt<4;nt++){ \
      bf8v k0 = *(const bf8v*)(Kc + kA + nt*2048 + kq0); \
      bf8v k1 = *(const bf8v*)(Kc + kA + nt*2048 + kq1); \
      _Pragma("unroll") \
      for(int qc=0;qc<2;qc++){ \
        f4v sv; float rh = qc ? rh1 : rh0; \
        for(int r=0;r<4;r++) sv[r] = rh + rw[nt][qc][r]; \
        __builtin_amdgcn_s_setprio(1); \
        sv = mfma32(k0, qa[qc][0], sv); \
        sv = mfma32(k1, qa[qc][1], sv); \
        __builtin_amdgcn_s_setprio(0); \
        f4v pe; \
        for(int r=0;r<4;r++) pe[r] = __builtin_amdgcn_exp2f(sv[r]); \
        p[nt][qc] = pe; } } \
    union U8 { u32 wd[4]; bf8v v; }; \
    U8 pb[2][2]; \
    _Pragma("unroll") \
    for(int half=0;half<2;half++) \
      for(int qc=0;qc<2;qc++) \
        for(int i=0;i<4;i++){ \
          int nt = half*2 + (i>>1), r0 = (i&1)*2; \
          asm("v_cvt_pk_bf16_f32 %0, %1, %2" \
              : "=v"(pb[half][qc].wd[i]) : "v"(p[nt][qc][r0]), "v"(p[nt][qc][r0+1])); } \
    _Pragma("unroll") \
    for(int qc=0;qc<2;qc++){ \
      psacc[qc] = mfma32(onesv, pb[0][qc].v, psacc[qc]); \
      psacc[qc] = mfma32(onesv, pb[1][qc].v, psacc[qc]); } \
    unsigned vcur = vbase + (CUR)*8192; \
    _Pragma("unroll") \
    for(int dt=0;dt<4;dt++){ \
      unsigned long t00,t01,t10,t11; \
      asm volatile( \
        "ds_read_b64_tr_b16 %0, %4 offset:%c5\n\t" \
        "ds_read_b64_tr_b16 %1, %4 offset:%c6\n\t" \
        "ds_read_b64_tr_b16 %2, %4 offset:%c7\n\t" \
        "ds_read_b64_tr_b16 %3, %4 offset:%c8\n\t" \
        "s_waitcnt lgkmcnt(0)" \
        : "=&v"(t00), "=&v"(t01), "=&v"(t10), "=&v"(t11) \
        : "v"(vcur), "i"((dt)*2048), "i"((dt)*2048+512), "i"((dt)*2048+1024), "i"((dt)*2048+1536) \
        : "memory"); \
      union PV { struct{ unsigned long a,b; } q; bf8v v; }; \
      PV v01, v23; \
      v01.q.a = t00; v01.q.b = t01; v23.q.a = t10; v23.q.b = t11; \
      __builtin_amdgcn_s_setprio(1); \
      _Pragma("unroll") \
      for(int qc=0;qc<2;qc++){ \
        oacc[dt][qc] = mfma32(v01.v, pb[0][qc].v, oacc[dt][qc]); \
        oacc[dt][qc] = mfma32(v23.v, pb[1][qc].v, oacc[dt][qc]); } \
      __builtin_amdgcn_s_setprio(0); } \
  }

__global__ __launch_bounds__(256,3) void qa_attn(
    const u16* __restrict__ qb, const u16* __restrict__ kb, const u16* __restrict__ vb,
    const u16* __restrict__ RHt, const u16* __restrict__ RW,
    u16* __restrict__ Op, float* __restrict__ Ps){
  __shared__ u16 Kl[2][4096];   // [buf][key][d], content at byte b = K[b ^ ((b>>7&7)<<4)]
  __shared__ u16 Vl[2][4096];   // [buf], subtiled: (d>>4)*2048B + key*32B + (d&15)*2B
  __shared__ u16 RHl[4096];     // [qhl][kh_local][qw]: 2 x 32 x 64
  const int t = threadIdx.x, lane = t&63, w = t>>6, c16 = lane&15, h4 = lane>>4;
  const int bid = blockIdx.x;
  const int g = (bid&7)*96 + (bid>>3);        // XCD swizzle (bijective, 768 % 8 == 0)
  const int s = g&1, u = g>>1;                // u in [0,384)
  const int head = u>>5, qblk = u&31;
  const int B0 = qblk*128;
  const int qhl = w>>1;                       // this wave's qh within block

  // prologue: stage RH [2][32][64] (two linear 4KB chunks; kh in [s*32, s*32+32))
  for(int i=0;i<2;i++){
    const u16* rhsrc = RHt + (((size_t)(head*64 + qblk*2 + i))*64 + s*32)*64;
    glds16(rhsrc + t*8, (u16*)RHl + i*2048 + w*512);
  }
  // staging source offsets (16B units), fold K swizzle / V subtile permutation into source
  int koff[2], voff[2];
  for(int i=0;i<2;i++){
    int uu = i*256 + t;
    koff[i] = (uu ^ ((uu>>3)&7))*8;                    // elements
    int key = ((uu>>1)&3) | (((uu>>3)&15)<<2);
    int d0  = ((uu&1)<<3) | (((uu>>7)&3)<<4);
    voff[i] = key*64 + d0;
  }
  const u16* kg = kb + (size_t)head*262144 + (size_t)s*131072;
  const u16* vg = vb + (size_t)head*262144 + (size_t)s*131072;
  const u16* kp = kg; const u16* vp = vg;
  for(int i=0;i<2;i++){                                 // tile 0 -> buf 0
    glds16(kp + koff[i], (u16*)Kl[0] + (i*256 + w*64)*8);
    glds16(vp + voff[i], (u16*)Vl[0] + (i*256 + w*64)*8);
  }
  kp += 4096; vp += 4096;

  // Q fragments (B-operand): lane holds Q[qrow = B0 + w*32 + qc*16 + c16][d = 8*h4+j]
  bf8v qa[2][2];
  for(int qc=0;qc<2;qc++){
    const u16* qsrc = qb + ((size_t)head*4096 + B0 + w*32 + qc*16 + c16)*64;
    qa[qc][0] = *(const bf8v*)(qsrc + h4*8);
    qa[qc][1] = *(const bf8v*)(qsrc + 32 + h4*8);
  }
  // RW bias in registers: rw[nt][qc][r] for kw = nt*16+4*h4+r (already *log2e)
  float rw[4][2][4];
  for(int nt=0;nt<4;nt++) for(int qc=0;qc<2;qc++) for(int r=0;r<4;r++){
    int qw = (w&1)*32 + qc*16 + c16, kw = nt*16 + 4*h4 + r;
    rw[nt][qc][r] = bf2f(RW[(((size_t)(head*64 + qblk*2 + qhl))*64 + qw)*64 + kw]);
  }
  bf8v onesv; for(int j=0;j<8;j++) onesv[j] = (short)0x3F80;  // bf16 1.0

  f4v oacc[4][2] = {}; f4v psacc[2] = {};
  const unsigned vbase = lds_off(Vl) + lane*8;
  const int kq0 = (h4*16) ^ ((c16&7)<<4);
  const int kq1 = (h4*16 + 64) ^ ((c16&7)<<4);
  const int kA  = c16*128;

  for(int itp=0; itp<16; itp++){
    AITER(2*itp, 0);
    AITER(2*itp+1, 1);
  }
  asm volatile("s_waitcnt vmcnt(0)" ::: "memory");  // drain wrap-around DMA before exit

  #pragma unroll
  for(int qc=0;qc<2;qc++){
    float v = psacc[qc][0];     // ones-MFMA row-sum: identical across h4/r, col = qrow = c16
    const int qrow_l = w*32 + qc*16 + c16;
    if(h4 == 0) Ps[((size_t)u*2 + s)*128 + qrow_l] = v;
    const size_t obase = (((size_t)u*2 + s)*128 + qrow_l)*64;
    #pragma unroll
    for(int dt=0;dt<4;dt++){
      u32x2 pk;
      asm("v_cvt_pk_bf16_f32 %0, %1, %2" : "=v"(pk[0]) : "v"(oacc[dt][qc][0]), "v"(oacc[dt][qc][1]));
      asm("v_cvt_pk_bf16_f32 %0, %1, %2" : "=v"(pk[1]) : "v"(oacc[dt][qc][2]), "v"(oacc[dt][qc][3]));
      *(u32x2*)&Op[obase + dt*16 + 4*h4] = pk;
    }
  }
}

// -------------- kernel 5b: split-K reduce: o = (O0+O1)/(s0+s1) --------------
__global__ __launch_bounds__(256) void qa_reduce(
    const u16* __restrict__ Op, const float* __restrict__ Ps, u16* __restrict__ ob){
  const int u = blockIdx.x, t = threadIdx.x;     // u in [0,384)
  const int head = u>>5, qblk = u&31;
  const int d0 = (t&15)*4;
  const size_t b0 = (size_t)u*2*128, b1 = b0 + 128;
  #pragma unroll
  for(int qq=0;qq<8;qq++){
    int qr = (t>>4) + qq*16;
    float inv = 1.0f / (Ps[b0 + qr] + Ps[b1 + qr]);
    u16x4 a = *(const u16x4*)&Op[(b0 + qr)*64 + d0];
    u16x4 b = *(const u16x4*)&Op[(b1 + qr)*64 + d0];
    u16x4 o;
    for(int j=0;j<4;j++) o[j] = f2bf((bf2f(a[j]) + bf2f(b[j]))*inv);
    *(u16x4*)&ob[(size_t)(qblk*128 + qr)*768 + head*64 + d0] = o;
  }
}

// -------------- kernel 6: output GEMM (4096 x 768 x 768) --------------
__global__ __launch_bounds__(256,2) void qa_gemm_out(
    const u16* __restrict__ A, const u16* __restrict__ Bt, const float* __restrict__ bias,
    float* __restrict__ out){
  __shared__ u16 Al[3][4096], Bl[3][4096];
  const int t = threadIdx.x, lane = t&63, w = t>>6, c16 = lane&15, h4 = lane>>4;
  const int m0 = blockIdx.y*128, n0 = blockIdx.x*128;
  const int wr = w>>1, wc = w&1;
  f4v acc[4][4];
  for(int nt=0;nt<4;nt++){
    f4v bv = *(const f4v*)&bias[n0 + wc*64 + nt*16 + 4*h4];
    for(int mt=0;mt<4;mt++) acc[mt][nt] = bv;
  }
  int srow[2], skk[2];
  for(int i=0;i<2;i++){
    int off = i*4096 + w*1024 + lane*16;
    srow[i] = off>>6; skk[i] = (off&63)>>1;
  }
  GEMM_STAGE(0, 0); GEMM_STAGE(32, 1);
  #pragma unroll
  for(int p=0;p<8;p++){ GEMM_STEP(3*p); GEMM_STEP(3*p+1); GEMM_STEP(3*p+2); }
  for(int mt=0;mt<4;mt++){
    int row = m0 + wr*64 + mt*16 + c16;
    for(int nt=0;nt<4;nt++){
      int col0 = n0 + wc*64 + nt*16 + 4*h4;
      *(f4v*)&out[(size_t)row*768 + col0] = acc[mt][nt];
    }
  }
}

extern "C" void kernel_launch(void* const* d_in, const int* in_sizes, int n_in,
                              void* d_out, int out_size, void* d_ws, size_t ws_size,
                              hipStream_t stream){
  const float* x    = (const float*)d_in[0];
  const float* wqkv = (const float*)d_in[1];
  const float* bqkv = (const float*)d_in[2];
  const float* wo   = (const float*)d_in[3];
  const float* bo   = (const float*)d_in[4];
  const float* rph  = (const float*)d_in[5];
  const float* rpw  = (const float*)d_in[6];
  float* out = (float*)d_out;

  size_t off = 0;
  auto alloc = [&](size_t bytes){ void* p = (char*)d_ws + off; off += (bytes + 255) & ~(size_t)255; return p; };
  u16* x_bf   = (u16*)alloc((size_t)HW*C*2);
  u16* wqkv_t = (u16*)alloc((size_t)2304*768*2);
  u16* wo_t   = (u16*)alloc((size_t)768*768*2);
  u16* q_buf  = (u16*)alloc((size_t)NH*HW*D*2);
  u16* k_buf  = (u16*)alloc((size_t)NH*HW*D*2);
  u16* v_buf  = (u16*)alloc((size_t)NH*HW*D*2);
  u16* rh_buf = (u16*)alloc((size_t)NH*64*64*64*2);
  u16* rw_buf = (u16*)alloc((size_t)NH*64*64*64*2);
  u16* o_buf  = (u16*)alloc((size_t)HW*C*2);
  u16* op_buf = (u16*)alloc((size_t)384*2*128*64*2);  // split-K partial O (bf16)
  float* ps_buf = (float*)alloc((size_t)384*2*128*4); // split-K partial sums

  qa_prep<<<5376, 256, 0, stream>>>(x, x_bf, wqkv, wqkv_t, wo, wo_t);
  qa_gemm_qkv<<<dim3(2304/128, HW/128), 256, 0, stream>>>(x_bf, wqkv_t, bqkv, q_buf, k_buf, v_buf);
  qa_rel<<<dim3(64, NH), 256, 0, stream>>>(q_buf, rph, rpw, rh_buf, rw_buf);
  qa_attn<<<768, 256, 0, stream>>>(q_buf, k_buf, v_buf, rh_buf, rw_buf, op_buf, ps_buf);
  qa_reduce<<<384, 256, 0, stream>>>(op_buf, ps_buf, o_buf);
  qa_gemm_out<<<dim3(768/128, HW/128), 256, 0, stream>>>(o_buf, wo_t, bo, out);
}

// Round 14
// 130.318 us; speedup vs baseline: 1.8475x; 1.0201x over previous
//
#include <hip/hip_runtime.h>

#define DEVI __device__ __forceinline__
typedef unsigned short u16;
typedef unsigned int u32;
typedef __attribute__((ext_vector_type(4))) float f4v;
typedef __attribute__((ext_vector_type(8))) short bf8v;   // 8 bf16 for MFMA A/B
typedef __attribute__((ext_vector_type(4))) u32  u32x4;
typedef __attribute__((ext_vector_type(2))) u32  u32x2;
typedef __attribute__((ext_vector_type(4))) u16  u16x4;

#define AS1 __attribute__((address_space(1)))
#define AS3 __attribute__((address_space(3)))

DEVI u16 f2bf(float x){ union{float f;u32 u;} c{x}; u32 r=(c.u+0x7FFFu+((c.u>>16)&1u))>>16; return (u16)r; }
DEVI float bf2f(u16 b){ union{u32 u;float f;} c{(u32)b<<16}; return c.f; }
DEVI f4v mfma32(bf8v a, bf8v b, f4v c){ return __builtin_amdgcn_mfma_f32_16x16x32_bf16(a,b,c,0,0,0); }
DEVI unsigned lds_off(const void* p){ return (unsigned)(unsigned long)(AS3 const void*)p; }
DEVI void glds16(const void* g, void* l){
  __builtin_amdgcn_global_load_lds((AS1 void*)g, (AS3 void*)l, 16, 0, 0);
}

static constexpr int NH = 12, HW = 4096, D = 64, C = 768;
static constexpr float LOG2E = 1.44269504f;

// -------------- kernel 1: fused prep: convx + transp(wqkv) + transp(wo) --------------
__global__ void qa_prep(const float* __restrict__ x, u16* __restrict__ xb,
                        const float* __restrict__ wqkv, u16* __restrict__ wqkvt,
                        const float* __restrict__ wo,   u16* __restrict__ wot){
  __shared__ float tl[32][33];
  const int b = blockIdx.x, t = threadIdx.x;
  if(b < 3072){                       // convx: 3072*256 f4v = 12*4096*64 floats
    int i = b*256 + t;
    f4v v = ((const f4v*)x)[i];
    u16x4 o; for(int j=0;j<4;j++) o[j] = f2bf(v[j]);
    ((u16x4*)xb)[i] = o;
    return;
  }
  const float* in; u16* out; int R, Cc, scale_k, bx, by;
  if(b < 3072 + 1728){ int bb = b - 3072; in = wqkv; out = wqkvt; R = 768; Cc = 2304; scale_k = 1; bx = bb % 72; by = bb / 72; }
  else               { int bb = b - 4800; in = wo;   out = wot;   R = 768; Cc = 768;  scale_k = 0; bx = bb % 24; by = bb / 24; }
  int r0 = by*32, c0 = bx*32;
  int tr = t>>3, tc = (t&7)*4;
  f4v v = *(const f4v*)&in[(r0+tr)*Cc + c0 + tc];
  for(int j=0;j<4;j++) tl[tr][tc+j] = v[j];
  __syncthreads();
  int oc = t>>3, orr = (t&7)*4;
  float sc = (scale_k && (c0+oc) >= 768 && (c0+oc) < 1536) ? 0.125f*LOG2E : 1.0f;
  u16x4 o; for(int j=0;j<4;j++) o[j] = f2bf(tl[orr+j][oc]*sc);
  *(u16x4*)&out[(c0+oc)*R + r0 + orr] = o;
}

// ---- pipelined-GEMM (3-buf, race-free: vmcnt before barrier, issue after) ----
#define GEMM_STAGE(K0, BUF) \
  for(int i=0;i<2;i++){ \
    glds16(A  + (size_t)(m0+srow[i])*768 + (K0) + skk[i], (u16*)Al[BUF] + i*2048 + w*512); \
    glds16(Bt + (size_t)(n0+srow[i])*768 + (K0) + skk[i], (u16*)Bl[BUF] + i*2048 + w*512); }

#define GEMM_STEP(KIDX) { \
  if((KIDX) < 23) asm volatile("s_waitcnt vmcnt(4)\n\ts_barrier" ::: "memory"); \
  else            asm volatile("s_waitcnt vmcnt(0)\n\ts_barrier" ::: "memory"); \
  if((KIDX)+2 < 24) GEMM_STAGE(((KIDX)+2)*32, ((KIDX)+2)%3); \
  const int CUR=(KIDX)%3; \
  bf8v a[4], b[4]; \
  for(int mt=0;mt<4;mt++) a[mt] = *(const bf8v*)&Al[CUR][(wr*64+mt*16+c16)*32 + h4*8]; \
  for(int nt=0;nt<4;nt++) b[nt] = *(const bf8v*)&Bl[CUR][(wc*64+nt*16+c16)*32 + h4*8]; \
  __builtin_amdgcn_s_setprio(1); \
  for(int mt=0;mt<4;mt++) for(int nt=0;nt<4;nt++) acc[mt][nt] = mfma32(b[nt], a[mt], acc[mt][nt]); \
  __builtin_amdgcn_s_setprio(0); }

// -------------- kernel 3: QKV GEMM (4096 x 2304 x 768) --------------
__global__ __launch_bounds__(256,2) void qa_gemm_qkv(
    const u16* __restrict__ A, const u16* __restrict__ Bt, const float* __restrict__ bias,
    u16* __restrict__ qb, u16* __restrict__ kb, u16* __restrict__ vb){
  __shared__ u16 Al[3][4096], Bl[3][4096];
  const int t = threadIdx.x, lane = t&63, w = t>>6, c16 = lane&15, h4 = lane>>4;
  const int m0 = blockIdx.y*128, n0 = blockIdx.x*128;
  const int wr = w>>1, wc = w&1;
  f4v acc[4][4];
  for(int nt=0;nt<4;nt++){
    f4v bv;
    for(int r=0;r<4;r++){
      int col = n0 + wc*64 + nt*16 + 4*h4 + r;
      float b = bias[col];
      bv[r] = (col >= 768 && col < 1536) ? b*0.125f*LOG2E : b;
    }
    for(int mt=0;mt<4;mt++) acc[mt][nt] = bv;
  }
  int srow[2], skk[2];
  for(int i=0;i<2;i++){
    int off = i*4096 + w*1024 + lane*16;
    srow[i] = off>>6; skk[i] = (off&63)>>1;
  }
  GEMM_STAGE(0, 0); GEMM_STAGE(32, 1);
  #pragma unroll
  for(int p=0;p<8;p++){ GEMM_STEP(3*p); GEMM_STEP(3*p+1); GEMM_STEP(3*p+2); }
  for(int mt=0;mt<4;mt++){
    int row = m0 + wr*64 + mt*16 + c16;
    for(int nt=0;nt<4;nt++){
      int col0 = n0 + wc*64 + nt*16 + 4*h4;
      int which = col0/768, head = (col0>>6)%12, d0 = col0&63;
      u16* dst = which==0 ? qb : (which==1 ? kb : vb);
      u32x2 pk;
      asm("v_cvt_pk_bf16_f32 %0, %1, %2" : "=v"(pk[0]) : "v"(acc[mt][nt][0]), "v"(acc[mt][nt][1]));
      asm("v_cvt_pk_bf16_f32 %0, %1, %2" : "=v"(pk[1]) : "v"(acc[mt][nt][2]), "v"(acc[mt][nt][3]));
      *(u32x2*)&dst[((size_t)(head<<12)+row)*64 + d0] = pk;
    }
  }
}

// -------------- kernel 4: rel-pos bias tables via MFMA (scaled by log2e) --------------
__global__ __launch_bounds__(256) void qa_rel(
    const u16* __restrict__ qbuf, const float* __restrict__ rph, const float* __restrict__ rpw,
    u16* __restrict__ RHt, u16* __restrict__ RW){
  const int t = threadIdx.x, lane = t&63, w = t>>6, c16 = lane&15, h4 = lane>>4;
  const int qh = blockIdx.x, head = blockIdx.y;
  __shared__ u16 ql[64*72], hl[64*72], wl[128*72];
  {
    int row = t>>2, d0 = (t&3)*16;
    const u16* src = qbuf + ((size_t)(head<<12)+(qh<<6)+row)*64 + d0;
    *(u32x4*)&ql[row*72+d0]   = *(const u32x4*)src;
    *(u32x4*)&ql[row*72+d0+8] = *(const u32x4*)(src+8);
    for(int j=0;j<16;j+=4){
      f4v v = *(const f4v*)&rph[(qh+row)*64 + d0 + j];
      u32x2 pk;
      asm("v_cvt_pk_bf16_f32 %0, %1, %2" : "=v"(pk[0]) : "v"(v[0]), "v"(v[1]));
      asm("v_cvt_pk_bf16_f32 %0, %1, %2" : "=v"(pk[1]) : "v"(v[2]), "v"(v[3]));
      *(u32x2*)&hl[row*72+d0+j] = pk;
    }
    int rw_r = t>>1, rd0 = (t&1)*32;
    if(rw_r < 127){
      for(int j=0;j<32;j+=4){
        f4v v = *(const f4v*)&rpw[rw_r*64+rd0+j];
        u32x2 pk;
        asm("v_cvt_pk_bf16_f32 %0, %1, %2" : "=v"(pk[0]) : "v"(v[0]), "v"(v[1]));
        asm("v_cvt_pk_bf16_f32 %0, %1, %2" : "=v"(pk[1]) : "v"(v[2]), "v"(v[3]));
        *(u32x2*)&wl[rw_r*72+rd0+j] = pk;
      }
    } else {
      for(int j=0;j<32;j+=4) *(u32x2*)&wl[rw_r*72+rd0+j] = (u32x2){0u,0u};
    }
  }
  __syncthreads();
  if(w < 2){
    bf8v a[2][2]; f4v acc[2][4] = {};
    for(int mt=0;mt<2;mt++) for(int ch=0;ch<2;ch++)
      a[mt][ch] = *(const bf8v*)&ql[(w*32+mt*16+c16)*72 + ch*32 + h4*8];
    for(int nt=0;nt<4;nt++) for(int ch=0;ch<2;ch++){
      bf8v b = *(const bf8v*)&hl[(nt*16+c16)*72 + ch*32 + h4*8];
      for(int mt=0;mt<2;mt++) acc[mt][nt] = mfma32(a[mt][ch], b, acc[mt][nt]);
    }
    for(int mt=0;mt<2;mt++) for(int nt=0;nt<4;nt++) for(int r=0;r<4;r++){
      int qw = w*32+mt*16+4*h4+r, c = nt*16+c16, kh = 63 - c;
      RHt[((size_t)(head*64+qh)*64+kh)*64 + qw] = f2bf(acc[mt][nt][r]*LOG2E);
    }
  } else {
    bf8v a[2][2]; f4v acc[2][8] = {};
    for(int mt=0;mt<2;mt++) for(int ch=0;ch<2;ch++)
      a[mt][ch] = *(const bf8v*)&ql[((w-2)*32+mt*16+c16)*72 + ch*32 + h4*8];
    for(int nt=0;nt<8;nt++) for(int ch=0;ch<2;ch++){
      bf8v b = *(const bf8v*)&wl[(nt*16+c16)*72 + ch*32 + h4*8];
      for(int mt=0;mt<2;mt++) acc[mt][nt] = mfma32(a[mt][ch], b, acc[mt][nt]);
    }
    for(int mt=0;mt<2;mt++) for(int nt=0;nt<8;nt++) for(int r=0;r<4;r++){
      int qw = (w-2)*32+mt*16+4*h4+r, c = nt*16+c16, kw = qw + 63 - c;
      if((unsigned)kw < 64u) RW[((size_t)(head*64+qh)*64+qw)*64 + kw] = f2bf(acc[mt][nt][r]*LOG2E);
    }
  }
}

// -------------- kernel 5: fused flash attention (R6/R9/R11-proven, byte-identical) --------------
// grid 768 (XCD-swizzled): block = (head, qblk of 128 rows, s); 4 waves x 32 qrows; 32 k-tiles.
#define AITER(IT, CUR) { \
    asm volatile("s_barrier" ::: "memory"); \
    if((IT) == 31){ kp = kg; vp = vg; } \
    { u16* Kn = (u16*)Kl[(CUR)^1]; u16* Vn = (u16*)Vl[(CUR)^1]; \
      for(int i=0;i<2;i++){ \
        glds16(kp + koff[i], Kn + (i*256 + w*64)*8); \
        glds16(vp + voff[i], Vn + (i*256 + w*64)*8); } } \
    kp += 4096; vp += 4096; \
    asm volatile("s_waitcnt vmcnt(4)" ::: "memory"); \
    const char* Kc = (const char*)Kl[CUR]; \
    float rh0 = bf2f(RHl[qhl*2048 + (IT)*64 + (w&1)*32 + c16]); \
    float rh1 = bf2f(RHl[qhl*2048 + (IT)*64 + (w&1)*32 + 16 + c16]); \
    f4v p[4][2]; \
    _Pragma("unroll") \
    for(int nt=0;nt<4;nt++){ \
      bf8v k0 = *(const bf8v*)(Kc + kA + nt*2048 + kq0); \
      bf8v k1 = *(const bf8v*)(Kc + kA + nt*2048 + kq1); \
      _Pragma("unroll") \
      for(int qc=0;qc<2;qc++){ \
        f4v sv; float rh = qc ? rh1 : rh0; \
        for(int r=0;r<4;r++) sv[r] = rh + rw[nt][qc][r]; \
        __builtin_amdgcn_s_setprio(1); \
        sv = mfma32(k0, qa[qc][0], sv); \
        sv = mfma32(k1, qa[qc][1], sv); \
        __builtin_amdgcn_s_setprio(0); \
        f4v pe; \
        for(int r=0;r<4;r++) pe[r] = __builtin_amdgcn_exp2f(sv[r]); \
        p[nt][qc] = pe; } } \
    union U8 { u32 wd[4]; bf8v v; }; \
    U8 pb[2][2]; \
    _Pragma("unroll") \
    for(int half=0;half<2;half++) \
      for(int qc=0;qc<2;qc++) \
        for(int i=0;i<4;i++){ \
          int nt = half*2 + (i>>1), r0 = (i&1)*2; \
          asm("v_cvt_pk_bf16_f32 %0, %1, %2" \
              : "=v"(pb[half][qc].wd[i]) : "v"(p[nt][qc][r0]), "v"(p[nt][qc][r0+1])); } \
    _Pragma("unroll") \
    for(int qc=0;qc<2;qc++){ \
      psacc[qc] = mfma32(onesv, pb[0][qc].v, psacc[qc]); \
      psacc[qc] = mfma32(onesv, pb[1][qc].v, psacc[qc]); } \
    unsigned vcur = vbase + (CUR)*8192; \
    _Pragma("unroll") \
    for(int dt=0;dt<4;dt++){ \
      unsigned long t00,t01,t10,t11; \
      asm volatile( \
        "ds_read_b64_tr_b16 %0, %4 offset:%c5\n\t" \
        "ds_read_b64_tr_b16 %1, %4 offset:%c6\n\t" \
        "ds_read_b64_tr_b16 %2, %4 offset:%c7\n\t" \
        "ds_read_b64_tr_b16 %3, %4 offset:%c8\n\t" \
        "s_waitcnt lgkmcnt(0)" \
        : "=&v"(t00), "=&v"(t01), "=&v"(t10), "=&v"(t11) \
        : "v"(vcur), "i"((dt)*2048), "i"((dt)*2048+512), "i"((dt)*2048+1024), "i"((dt)*2048+1536) \
        : "memory"); \
      union PV { struct{ unsigned long a,b; } q; bf8v v; }; \
      PV v01, v23; \
      v01.q.a = t00; v01.q.b = t01; v23.q.a = t10; v23.q.b = t11; \
      __builtin_amdgcn_s_setprio(1); \
      _Pragma("unroll") \
      for(int qc=0;qc<2;qc++){ \
        oacc[dt][qc] = mfma32(v01.v, pb[0][qc].v, oacc[dt][qc]); \
        oacc[dt][qc] = mfma32(v23.v, pb[1][qc].v, oacc[dt][qc]); } \
      __builtin_amdgcn_s_setprio(0); } \
  }

__global__ __launch_bounds__(256,3) void qa_attn(
    const u16* __restrict__ qb, const u16* __restrict__ kb, const u16* __restrict__ vb,
    const u16* __restrict__ RHt, const u16* __restrict__ RW,
    u16* __restrict__ Op, float* __restrict__ Ps){
  __shared__ u16 Kl[2][4096];   // [buf][key][d], content at byte b = K[b ^ ((b>>7&7)<<4)]
  __shared__ u16 Vl[2][4096];   // [buf], subtiled: (d>>4)*2048B + key*32B + (d&15)*2B
  __shared__ u16 RHl[4096];     // [qhl][kh_local][qw]: 2 x 32 x 64
  const int t = threadIdx.x, lane = t&63, w = t>>6, c16 = lane&15, h4 = lane>>4;
  const int bid = blockIdx.x;
  const int g = (bid&7)*96 + (bid>>3);        // XCD swizzle (bijective, 768 % 8 == 0)
  const int s = g&1, u = g>>1;                // u in [0,384)
  const int head = u>>5, qblk = u&31;
  const int B0 = qblk*128;
  const int qhl = w>>1;                       // this wave's qh within block

  // prologue: stage RH [2][32][64] (two linear 4KB chunks; kh in [s*32, s*32+32))
  for(int i=0;i<2;i++){
    const u16* rhsrc = RHt + (((size_t)(head*64 + qblk*2 + i))*64 + s*32)*64;
    glds16(rhsrc + t*8, (u16*)RHl + i*2048 + w*512);
  }
  // staging source offsets (16B units), fold K swizzle / V subtile permutation into source
  int koff[2], voff[2];
  for(int i=0;i<2;i++){
    int uu = i*256 + t;
    koff[i] = (uu ^ ((uu>>3)&7))*8;                    // elements
    int key = ((uu>>1)&3) | (((uu>>3)&15)<<2);
    int d0  = ((uu&1)<<3) | (((uu>>7)&3)<<4);
    voff[i] = key*64 + d0;
  }
  const u16* kg = kb + (size_t)head*262144 + (size_t)s*131072;
  const u16* vg = vb + (size_t)head*262144 + (size_t)s*131072;
  const u16* kp = kg; const u16* vp = vg;
  for(int i=0;i<2;i++){                                 // tile 0 -> buf 0
    glds16(kp + koff[i], (u16*)Kl[0] + (i*256 + w*64)*8);
    glds16(vp + voff[i], (u16*)Vl[0] + (i*256 + w*64)*8);
  }
  kp += 4096; vp += 4096;

  // Q fragments (B-operand): lane holds Q[qrow = B0 + w*32 + qc*16 + c16][d = 8*h4+j]
  bf8v qa[2][2];
  for(int qc=0;qc<2;qc++){
    const u16* qsrc = qb + ((size_t)head*4096 + B0 + w*32 + qc*16 + c16)*64;
    qa[qc][0] = *(const bf8v*)(qsrc + h4*8);
    qa[qc][1] = *(const bf8v*)(qsrc + 32 + h4*8);
  }
  // RW bias in registers: rw[nt][qc][r] for kw = nt*16+4*h4+r (already *log2e)
  float rw[4][2][4];
  for(int nt=0;nt<4;nt++) for(int qc=0;qc<2;qc++) for(int r=0;r<4;r++){
    int qw = (w&1)*32 + qc*16 + c16, kw = nt*16 + 4*h4 + r;
    rw[nt][qc][r] = bf2f(RW[(((size_t)(head*64 + qblk*2 + qhl))*64 + qw)*64 + kw]);
  }
  bf8v onesv; for(int j=0;j<8;j++) onesv[j] = (short)0x3F80;  // bf16 1.0

  f4v oacc[4][2] = {}; f4v psacc[2] = {};
  const unsigned vbase = lds_off(Vl) + lane*8;
  const int kq0 = (h4*16) ^ ((c16&7)<<4);
  const int kq1 = (h4*16 + 64) ^ ((c16&7)<<4);
  const int kA  = c16*128;

  for(int itp=0; itp<16; itp++){
    AITER(2*itp, 0);
    AITER(2*itp+1, 1);
  }
  asm volatile("s_waitcnt vmcnt(0)" ::: "memory");  // drain wrap-around DMA before exit

  #pragma unroll
  for(int qc=0;qc<2;qc++){
    float v = psacc[qc][0];     // ones-MFMA row-sum: identical across h4/r, col = qrow = c16
    const int qrow_l = w*32 + qc*16 + c16;
    if(h4 == 0) Ps[((size_t)u*2 + s)*128 + qrow_l] = v;
    const size_t obase = (((size_t)u*2 + s)*128 + qrow_l)*64;
    #pragma unroll
    for(int dt=0;dt<4;dt++){
      u32x2 pk;
      asm("v_cvt_pk_bf16_f32 %0, %1, %2" : "=v"(pk[0]) : "v"(oacc[dt][qc][0]), "v"(oacc[dt][qc][1]));
      asm("v_cvt_pk_bf16_f32 %0, %1, %2" : "=v"(pk[1]) : "v"(oacc[dt][qc][2]), "v"(oacc[dt][qc][3]));
      *(u32x2*)&Op[obase + dt*16 + 4*h4] = pk;
    }
  }
}

// -------------- kernel 5b: split-K reduce: o = (O0+O1)/(s0+s1) --------------
__global__ __launch_bounds__(256) void qa_reduce(
    const u16* __restrict__ Op, const float* __restrict__ Ps, u16* __restrict__ ob){
  const int u = blockIdx.x, t = threadIdx.x;     // u in [0,384)
  const int head = u>>5, qblk = u&31;
  const int d0 = (t&15)*4;
  const size_t b0 = (size_t)u*2*128, b1 = b0 + 128;
  #pragma unroll
  for(int qq=0;qq<8;qq++){
    int qr = (t>>4) + qq*16;
    float inv = 1.0f / (Ps[b0 + qr] + Ps[b1 + qr]);
    u16x4 a = *(const u16x4*)&Op[(b0 + qr)*64 + d0];
    u16x4 b = *(const u16x4*)&Op[(b1 + qr)*64 + d0];
    u16x4 o;
    for(int j=0;j<4;j++) o[j] = f2bf((bf2f(a[j]) + bf2f(b[j]))*inv);
    *(u16x4*)&ob[(size_t)(qblk*128 + qr)*768 + head*64 + d0] = o;
  }
}

// -------------- kernel 6: output GEMM (4096 x 768 x 768), 64x64 tiles for full fill --------------
// grid (12,64) = 768 blocks = 3 blocks/CU (vs 192 = 0.75/CU at 128x128).
// Same proven 3-buf protocol; constants re-derived: 1 glds16 pair/thread/step, vmcnt(2).
#define GOUT_STAGE(K0, BUF) { \
    glds16(A  + (size_t)(m0 + (t>>2))*768 + (K0) + (t&3)*8, (u16*)Al[BUF] + t*8); \
    glds16(Bt + (size_t)(n0 + (t>>2))*768 + (K0) + (t&3)*8, (u16*)Bl[BUF] + t*8); }

#define GOUT_STEP(KIDX) { \
  if((KIDX) < 23) asm volatile("s_waitcnt vmcnt(2)\n\ts_barrier" ::: "memory"); \
  else            asm volatile("s_waitcnt vmcnt(0)\n\ts_barrier" ::: "memory"); \
  if((KIDX)+2 < 24) GOUT_STAGE(((KIDX)+2)*32, ((KIDX)+2)%3); \
  const int CUR=(KIDX)%3; \
  bf8v a[2], b[2]; \
  for(int mt=0;mt<2;mt++) a[mt] = *(const bf8v*)&Al[CUR][(wr*32+mt*16+c16)*32 + h4*8]; \
  for(int nt=0;nt<2;nt++) b[nt] = *(const bf8v*)&Bl[CUR][(wc*32+nt*16+c16)*32 + h4*8]; \
  __builtin_amdgcn_s_setprio(1); \
  for(int mt=0;mt<2;mt++) for(int nt=0;nt<2;nt++) acc[mt][nt] = mfma32(b[nt], a[mt], acc[mt][nt]); \
  __builtin_amdgcn_s_setprio(0); }

__global__ __launch_bounds__(256,4) void qa_gemm_out(
    const u16* __restrict__ A, const u16* __restrict__ Bt, const float* __restrict__ bias,
    float* __restrict__ out){
  __shared__ u16 Al[3][2048], Bl[3][2048];
  const int t = threadIdx.x, lane = t&63, w = t>>6, c16 = lane&15, h4 = lane>>4;
  const int m0 = blockIdx.y*64, n0 = blockIdx.x*64;
  const int wr = w>>1, wc = w&1;
  f4v acc[2][2];
  for(int nt=0;nt<2;nt++){
    f4v bv = *(const f4v*)&bias[n0 + wc*32 + nt*16 + 4*h4];
    for(int mt=0;mt<2;mt++) acc[mt][nt] = bv;
  }
  GOUT_STAGE(0, 0); GOUT_STAGE(32, 1);
  #pragma unroll
  for(int p=0;p<8;p++){ GOUT_STEP(3*p); GOUT_STEP(3*p+1); GOUT_STEP(3*p+2); }
  for(int mt=0;mt<2;mt++){
    int row = m0 + wr*32 + mt*16 + c16;
    for(int nt=0;nt<2;nt++){
      int col0 = n0 + wc*32 + nt*16 + 4*h4;
      *(f4v*)&out[(size_t)row*768 + col0] = acc[mt][nt];
    }
  }
}

extern "C" void kernel_launch(void* const* d_in, const int* in_sizes, int n_in,
                              void* d_out, int out_size, void* d_ws, size_t ws_size,
                              hipStream_t stream){
  const float* x    = (const float*)d_in[0];
  const float* wqkv = (const float*)d_in[1];
  const float* bqkv = (const float*)d_in[2];
  const float* wo   = (const float*)d_in[3];
  const float* bo   = (const float*)d_in[4];
  const float* rph  = (const float*)d_in[5];
  const float* rpw  = (const float*)d_in[6];
  float* out = (float*)d_out;

  size_t off = 0;
  auto alloc = [&](size_t bytes){ void* p = (char*)d_ws + off; off += (bytes + 255) & ~(size_t)255; return p; };
  u16* x_bf   = (u16*)alloc((size_t)HW*C*2);
  u16* wqkv_t = (u16*)alloc((size_t)2304*768*2);
  u16* wo_t   = (u16*)alloc((size_t)768*768*2);
  u16* q_buf  = (u16*)alloc((size_t)NH*HW*D*2);
  u16* k_buf  = (u16*)alloc((size_t)NH*HW*D*2);
  u16* v_buf  = (u16*)alloc((size_t)NH*HW*D*2);
  u16* rh_buf = (u16*)alloc((size_t)NH*64*64*64*2);
  u16* rw_buf = (u16*)alloc((size_t)NH*64*64*64*2);
  u16* o_buf  = (u16*)alloc((size_t)HW*C*2);
  u16* op_buf = (u16*)alloc((size_t)384*2*128*64*2);  // split-K partial O (bf16)
  float* ps_buf = (float*)alloc((size_t)384*2*128*4); // split-K partial sums

  qa_prep<<<5376, 256, 0, stream>>>(x, x_bf, wqkv, wqkv_t, wo, wo_t);
  qa_gemm_qkv<<<dim3(2304/128, HW/128), 256, 0, stream>>>(x_bf, wqkv_t, bqkv, q_buf, k_buf, v_buf);
  qa_rel<<<dim3(64, NH), 256, 0, stream>>>(q_buf, rph, rpw, rh_buf, rw_buf);
  qa_attn<<<768, 256, 0, stream>>>(q_buf, k_buf, v_buf, rh_buf, rw_buf, op_buf, ps_buf);
  qa_reduce<<<384, 256, 0, stream>>>(op_buf, ps_buf, o_buf);
  qa_gemm_out<<<dim3(768/64, 4096/64), 256, 0, stream>>>(o_buf, wo_t, bo, out);
}